// Round 8
// baseline (139.502 us; speedup 1.0000x reference)
//
#include <hip/hip_runtime.h>
#include <hip/hip_bf16.h>

#define Bsz 4
#define Lsz 2048
#define Hsz 8

typedef __attribute__((ext_vector_type(8))) short bf16x8;
typedef __attribute__((ext_vector_type(4))) short bf16x4;
typedef __attribute__((ext_vector_type(4))) float f32x4;

__device__ __forceinline__ short f2bs(float f) {   // RNE, prep only
    union { float f; unsigned u; } v; v.f = f;
    unsigned r = v.u + 0x7FFFu + ((v.u >> 16) & 1u);
    return (short)(r >> 16);
}
__device__ __forceinline__ short f2bs_rh(float f) { // round-half-up, 2 ops
    return (short)((__float_as_uint(f) + 0x8000u) >> 16);
}

// async global->LDS, 16B per lane; LDS dest is wave-uniform base + lane*16
__device__ __forceinline__ void stage16(const short* g, short* l) {
    __builtin_amdgcn_global_load_lds(
        (const __attribute__((address_space(1))) unsigned int*)g,
        (__attribute__((address_space(3))) unsigned int*)l,
        16, 0, 0);
}

// ---------------- fused pre-pass: K and V -> bf16 MFMA fragments ----------------
// Per (bh, 64-key tile): 8 chunks x 1024 B, frag position = lane (conflict-free
// lane-linear LDS reads in main).
// K chunk c=nt*2+eh, lane(quad,ln): K[k0+nt*16+ln][eh*32+quad*8+j]  (A-op 16x16x32)
// V chunk c=m16*2+ntp, lane: 16B = [frag(nt=2ntp) | frag(nt=2ntp+1)], each
//   frag = V[k0+nt*16+quad*4+j][m16*16+ln] j=0..3                   (A-op 16x16x16)
__global__ __launch_bounds__(256) void prep_kv(
    const float* __restrict__ ksrc, const float* __restrict__ vsrc,
    short* __restrict__ Kf, short* __restrict__ Vf)
{
    __shared__ float Tl[64][65];
    const int raw = blockIdx.x;
    const int tid = threadIdx.x;
    const bool isK = raw < Bsz*Hsz*32;
    const int bid = isK ? raw : raw - Bsz*Hsz*32;
    const int tl = bid & 31, bh = bid >> 5;
    const int b = bh >> 3, h = bh & 7;

    // coalesced stage of the 64x64 fp32 tile
    const int row = tid >> 2, c0 = (tid & 3) * 16;
    const float* src = (isK ? ksrc : vsrc)
                     + (((size_t)b*Lsz + tl*64 + row)*Hsz + h)*64 + c0;
    *(float4*)&Tl[row][c0]      = *(const float4*)(src);
    *(float4*)&Tl[row][c0 + 4]  = *(const float4*)(src + 4);
    *(float4*)&Tl[row][c0 + 8]  = *(const float4*)(src + 8);
    *(float4*)&Tl[row][c0 + 12] = *(const float4*)(src + 12);
    __syncthreads();

    const int lane = tid & 63, ln = lane & 15, quad = lane >> 4;
    if (isK) {
        short* dst = Kf + (size_t)bid * 4096;
        #pragma unroll
        for (int cc = 0; cc < 2; ++cc) {
            const int c  = (tid >> 6)*2 + cc;
            const int nt = c >> 1, eh = c & 1;
            const float* rp = &Tl[nt*16 + ln][eh*32 + quad*8];
            bf16x8 o = {f2bs(rp[0]),f2bs(rp[1]),f2bs(rp[2]),f2bs(rp[3]),
                        f2bs(rp[4]),f2bs(rp[5]),f2bs(rp[6]),f2bs(rp[7])};
            *(bf16x8*)(dst + c*512 + lane*8) = o;
        }
    } else {
        short* dst = Vf + (size_t)bid * 4096;
        #pragma unroll
        for (int cc = 0; cc < 2; ++cc) {
            const int cp  = (tid >> 6)*2 + cc;
            const int m16 = cp >> 1, nt0 = (cp & 1)*2;
            const int d   = m16*16 + ln;
            const int s0  = nt0*16 + quad*4;
            bf16x8 o = {f2bs(Tl[s0+0][d]),  f2bs(Tl[s0+1][d]),
                        f2bs(Tl[s0+2][d]),  f2bs(Tl[s0+3][d]),
                        f2bs(Tl[s0+16][d]), f2bs(Tl[s0+17][d]),
                        f2bs(Tl[s0+18][d]), f2bs(Tl[s0+19][d])};
            *(bf16x8*)(dst + cp*512 + lane*8) = o;
        }
    }
}

// ---------------- main: key-split S^T flash attention ----------------
// 256 thr = 4 waves; wave (qh=wv>>1, kh=wv&1) owns 32 q-rows x 32 keys:
// halves the per-wave LDS tile reads vs all-keys-per-wave. Epilogue does a
// one-time cross-wave-pair O/l reduction via LDS (overlaying dead staging).
// S^T = mfma_16x16x32(kf, qf): C-layout key=quad*4+r, q=ln == B-operand of
// mfma_16x16x16 -> P^T feeds O^T = V^T P^T directly from registers.
// No-max softmax (|logit*log2e*scale*tau| <= ~13.5, l <= 2.4e7: fp32-safe).
__global__ __launch_bounds__(256, 4) void dsattn_main(
    const float* __restrict__ q,
    const short* __restrict__ Kf,
    const short* __restrict__ Vf,
    const float* __restrict__ tau,
    const float* __restrict__ delta,
    float* __restrict__ out)
{
    // 40 KB carved: Kb dbuf 16K | Vb dbuf 16K | dls 8K.
    // Epilogue overlays [0,21K): osc 18.4K + lx 0.5K (staging is dead by then).
    __shared__ __align__(16) char smem[40960];
    short* KbBase = (short*)smem;                  // [2][4096]
    short* VbBase = (short*)(smem + 16384);        // [2][4096]
    float* dls    = (float*)(smem + 32768);        // [2048]

    const int tid  = threadIdx.x;
    const int wv   = tid >> 6;
    const int lane = tid & 63;
    const int ln   = lane & 15;
    const int quad = lane >> 4;
    const int qh   = wv >> 1;           // q-half (32 rows)
    const int kh   = wv & 1;            // key-half (32 keys)

    const int bh = blockIdx.x;
    const int b  = bh >> 3, h = bh & 7;
    // co-resident y-group {y0,y0+8,y0+16,y0+24} -> qt {a,15-a,16+a,31-a}: 66 tiles/CU
    const int j  = blockIdx.y, aj = j & 7, gj = j >> 3;
    const int qt = (gj == 0) ? aj : (gj == 1) ? 15 - aj
                 : (gj == 2) ? 16 + aj : 31 - aj;
    const int q0 = qt * 64;
    const int T  = qt + 1;

    const float c2  = 0.125f * 1.44269504f;   // scale * log2(e)
    const float st2 = c2 * tau[b];

    const short* kt = Kf + (size_t)bh * (32*4096);
    const short* vt = Vf + (size_t)bh * (32*4096);

    // stage c2*delta (256 thr x 8 floats)
    {
        const float* dsrc = delta + (size_t)b*Lsz + tid*8;
        float4 a = *(const float4*)(dsrc);
        float4 c = *(const float4*)(dsrc + 4);
        a.x*=c2; a.y*=c2; a.z*=c2; a.w*=c2;
        c.x*=c2; c.y*=c2; c.z*=c2; c.w*=c2;
        *(float4*)&dls[tid*8]     = a;
        *(float4*)&dls[tid*8 + 4] = c;
    }

    // stage tile 0 (16 chunks of 1KB; wave wv does chunks wv*4..+3)
    #pragma unroll
    for (int u = 0; u < 4; ++u) {
        const int c = wv*4 + u;
        const short* g = ((c < 8) ? kt : vt) + (c & 7)*512 + lane*8;
        short* l = ((c < 8) ? KbBase : VbBase) + (c & 7)*512;
        stage16(g, l);
    }

    // Q fragments for the wave's two 16-row q-blocks (B-operand of 16x16x32)
    const int qbase = q0 + qh*32;
    bf16x8 qf[2][2];
    #pragma unroll
    for (int qm = 0; qm < 2; ++qm) {
        const float* qrow = q + (((size_t)b*Lsz + qbase + qm*16 + ln)*Hsz + h)*64;
        float4 a0 = *(const float4*)(qrow + quad*8);
        float4 a1 = *(const float4*)(qrow + quad*8 + 4);
        float4 b0 = *(const float4*)(qrow + 32 + quad*8);
        float4 b1 = *(const float4*)(qrow + 32 + quad*8 + 4);
        qf[qm][0] = (bf16x8){f2bs(a0.x),f2bs(a0.y),f2bs(a0.z),f2bs(a0.w),
                             f2bs(a1.x),f2bs(a1.y),f2bs(a1.z),f2bs(a1.w)};
        qf[qm][1] = (bf16x8){f2bs(b0.x),f2bs(b0.y),f2bs(b0.z),f2bs(b0.w),
                             f2bs(b1.x),f2bs(b1.y),f2bs(b1.z),f2bs(b1.w)};
    }

    f32x4 oacc[4][2];                    // [m16][qm] : O^T[d=m16*16+quad*4+r][q=qm*16+ln]
    #pragma unroll
    for (int m = 0; m < 4; ++m)
        #pragma unroll
        for (int qm = 0; qm < 2; ++qm) oacc[m][qm] = (f32x4){0.f,0.f,0.f,0.f};
    float l_acc[2] = {0.f, 0.f};

    __syncthreads();   // tile 0 + dls staged (barrier drains vmcnt)

    for (int t = 0; t < T; ++t) {
        const int cur = t & 1;
        if (t + 1 < T) {                       // stream tile t+1 into other buffer
            const int nb = cur ^ 1;
            #pragma unroll
            for (int u = 0; u < 4; ++u) {
                const int c = wv*4 + u;
                const short* g = ((c < 8) ? kt : vt)
                               + (size_t)(t+1)*4096 + (c & 7)*512 + lane*8;
                short* l = ((c < 8) ? KbBase : VbBase) + nb*4096 + (c & 7)*512;
                stage16(g, l);
            }
        }

        // wave (qh=0, kh=1) is fully masked on the diagonal tile -> skip compute
        if (!(t == qt && qh == 0 && kh == 1)) {
            const short* Kc = KbBase + cur*4096;
            const short* Vc = VbBase + cur*4096;
            const int k0 = t*64;

            // K frags for this wave's 32 keys (nt in {2kh, 2kh+1})
            bf16x8 kfr[2][2];
            #pragma unroll
            for (int nl = 0; nl < 2; ++nl)
                #pragma unroll
                for (int eh = 0; eh < 2; ++eh)
                    kfr[nl][eh] = *(const bf16x8*)(Kc + ((2*kh+nl)*2+eh)*512 + lane*8);

            // S^T: lane holds [key=k0+kh*32+nl*16+quad*4+r][q=qbase+qm*16+ln]
            f32x4 sacc[2][2];
            #pragma unroll
            for (int qm = 0; qm < 2; ++qm)
                #pragma unroll
                for (int nl = 0; nl < 2; ++nl) {
                    f32x4 z = (f32x4){0.f,0.f,0.f,0.f};
                    z = __builtin_amdgcn_mfma_f32_16x16x32_bf16(kfr[nl][0], qf[qm][0], z, 0,0,0);
                    sacc[qm][nl] = __builtin_amdgcn_mfma_f32_16x16x32_bf16(kfr[nl][1], qf[qm][1], z, 0,0,0);
                }

            f32x4 dlv[2];
            #pragma unroll
            for (int nl = 0; nl < 2; ++nl)
                dlv[nl] = *(const f32x4*)&dls[k0 + kh*32 + nl*16 + quad*4];

            if (t == qt) {                     // diagonal tile: causal mask
                #pragma unroll
                for (int qm = 0; qm < 2; ++qm) {
                    const int qrow = qbase + qm*16 + ln;
                    #pragma unroll
                    for (int nl = 0; nl < 2; ++nl)
                        #pragma unroll
                        for (int r = 0; r < 4; ++r)
                            if (k0 + kh*32 + nl*16 + quad*4 + r > qrow)
                                sacc[qm][nl][r] = -1e30f;
                }
            }

            bf16x4 pT[2][2];
            #pragma unroll
            for (int qm = 0; qm < 2; ++qm)
                #pragma unroll
                for (int nl = 0; nl < 2; ++nl) {
                    float p0 = __builtin_amdgcn_exp2f(fmaf(sacc[qm][nl][0], st2, dlv[nl][0]));
                    float p1 = __builtin_amdgcn_exp2f(fmaf(sacc[qm][nl][1], st2, dlv[nl][1]));
                    float p2 = __builtin_amdgcn_exp2f(fmaf(sacc[qm][nl][2], st2, dlv[nl][2]));
                    float p3 = __builtin_amdgcn_exp2f(fmaf(sacc[qm][nl][3], st2, dlv[nl][3]));
                    l_acc[qm] += (p0 + p1) + (p2 + p3);
                    pT[qm][nl] = (bf16x4){f2bs_rh(p0), f2bs_rh(p1), f2bs_rh(p2), f2bs_rh(p3)};
                }

            // O^T += V^T P^T over this wave's 32 keys (V chunk ntp = kh)
            #pragma unroll
            for (int m16 = 0; m16 < 4; ++m16) {
                bf16x8 vv = *(const bf16x8*)(Vc + (m16*2+kh)*512 + lane*8);
                bf16x4 v0 = (bf16x4){vv[0], vv[1], vv[2], vv[3]};
                bf16x4 v1 = (bf16x4){vv[4], vv[5], vv[6], vv[7]};
                #pragma unroll
                for (int qm = 0; qm < 2; ++qm) {
                    oacc[m16][qm] = __builtin_amdgcn_mfma_f32_16x16x16bf16_1k(
                        v0, pT[qm][0], oacc[m16][qm], 0,0,0);
                    oacc[m16][qm] = __builtin_amdgcn_mfma_f32_16x16x16bf16_1k(
                        v1, pT[qm][1], oacc[m16][qm], 0,0,0);
                }
            }
        }

        __syncthreads();   // staged t+1 complete + all reads of cur done
    }

    // ---- epilogue: cross-wave-pair (kh0,kh1) O/l reduce via LDS overlay ----
    float* osc = (float*)smem;             // [4][32 q][36]  (18.4 KB, over staging)
    float* lx  = (float*)(smem + 20480);   // [4][2][16]

    float lt[2];
    #pragma unroll
    for (int qm = 0; qm < 2; ++qm) {
        float ls = l_acc[qm];
        ls += __shfl_xor(ls, 16, 64);
        ls += __shfl_xor(ls, 32, 64);
        lt[qm] = ls;
        if (quad == 0) lx[(wv*2+qm)*16 + ln] = ls;
    }
    // write the m16 pair this wave does NOT store (partner stores it)
    const int wr0 = (1 - kh) * 2;          // m16 base written to LDS
    #pragma unroll
    for (int mm = 0; mm < 2; ++mm)
        #pragma unroll
        for (int qm = 0; qm < 2; ++qm) {
            f32x4 o = oacc[wr0+mm][qm];
            *(float4*)&osc[(wv*32 + qm*16 + ln)*36 + mm*16 + quad*4] =
                (float4){o[0], o[1], o[2], o[3]};
        }
    __syncthreads();

    const int pw = wv ^ 1;                 // partner wave (other key-half, same qh)
    const int st0 = kh * 2;                // m16 base this wave stores
    float inv[2];
    #pragma unroll
    for (int qm = 0; qm < 2; ++qm)
        inv[qm] = 1.0f / (lt[qm] + lx[(pw*2+qm)*16 + ln]);
    #pragma unroll
    for (int mm = 0; mm < 2; ++mm)
        #pragma unroll
        for (int qm = 0; qm < 2; ++qm) {
            const int m16 = st0 + mm;
            float4 add = *(const float4*)&osc[(pw*32 + qm*16 + ln)*36 + mm*16 + quad*4];
            f32x4 o = oacc[m16][qm];
            float4 res = {(o[0]+add.x)*inv[qm], (o[1]+add.y)*inv[qm],
                          (o[2]+add.z)*inv[qm], (o[3]+add.w)*inv[qm]};
            const int qrow = qbase + qm*16 + ln;
            *(float4*)(out + (((size_t)b*Lsz + qrow)*Hsz + h)*64 + m16*16 + quad*4) = res;
        }
}

extern "C" void kernel_launch(void* const* d_in, const int* in_sizes, int n_in,
                              void* d_out, int out_size, void* d_ws, size_t ws_size,
                              hipStream_t stream) {
    (void)in_sizes; (void)n_in; (void)out_size; (void)ws_size;
    const float* q     = (const float*)d_in[0];
    const float* k     = (const float*)d_in[1];
    const float* v     = (const float*)d_in[2];
    const float* tau   = (const float*)d_in[3];
    const float* delta = (const float*)d_in[4];
    float* out = (float*)d_out;

    short* Kf = (short*)d_ws;                          // 8 MiB bf16 fragments
    short* Vf = (short*)d_ws + (size_t)(4*1024*1024);  // next 8 MiB

    prep_kv<<<dim3(Bsz*Hsz*32*2), dim3(256), 0, stream>>>(k, v, Kf, Vf);
    dsattn_main<<<dim3(Bsz*Hsz, 32), dim3(256), 0, stream>>>(q, Kf, Vf, tau, delta, out);
}